// Round 8
// baseline (225.855 us; speedup 1.0000x reference)
//
#include <hip/hip_runtime.h>
#include <cstdint>

#define KCODES 1024
#define OUT_LOSS 8388608   // B*D
#define OUT_IDX  8388610   // B*D + 2 losses

typedef short bf16x8 __attribute__((ext_vector_type(8)));
typedef float f32x4  __attribute__((ext_vector_type(4)));
typedef unsigned u32x4 __attribute__((ext_vector_type(4)));

__device__ __forceinline__ unsigned short f2bf_rne(float f) {
    unsigned u = __float_as_uint(f);
    u += 0x7fffu + ((u >> 16) & 1u);
    return (unsigned short)(u >> 16);
}
__device__ __forceinline__ void split_pair(float a, float b, unsigned& hi, unsigned& lo) {
    unsigned ha = f2bf_rne(a), hb = f2bf_rne(b);
    hi = ha | (hb << 16);
    float ra = a - __uint_as_float(ha << 16);
    float rb = b - __uint_as_float(hb << 16);
    lo = (unsigned)f2bf_rne(ra) | ((unsigned)f2bf_rne(rb) << 16);
}

#define SPLIT8(P, Q, HV, LV) do {                                         \
    unsigned h0_,h1_,h2_,h3_,l0_,l1_,l2_,l3_;                             \
    split_pair((P).x,(P).y,h0_,l0_); split_pair((P).z,(P).w,h1_,l1_);     \
    split_pair((Q).x,(Q).y,h2_,l2_); split_pair((Q).z,(Q).w,h3_,l3_);     \
    HV = __builtin_bit_cast(bf16x8,(u32x4){h0_,h1_,h2_,h3_});             \
    LV = __builtin_bit_cast(bf16x8,(u32x4){l0_,l1_,l2_,l3_});             \
} while(0)

// ---------------------------------------------------------------------------
// k_prep: W bf16 hi/lo split + wsqh[c] = -0.5*|W_c|^2 (MFMA C-operand init).
// ---------------------------------------------------------------------------
__global__ __launch_bounds__(256) void k_prep(const float* __restrict__ W,
                                              short* __restrict__ w_hi,
                                              short* __restrict__ w_lo,
                                              float* __restrict__ wsqh) {
    const int c = blockIdx.x * 256 + threadIdx.x;
    const float4* wr = (const float4*)(W + (c << 6));
    float a0 = 0.f, a1 = 0.f, a2 = 0.f, a3 = 0.f;
#pragma unroll
    for (int j = 0; j < 8; ++j) {
        float4 p = wr[2 * j], q = wr[2 * j + 1];
        a0 = fmaf(p.x, p.x, a0); a1 = fmaf(p.y, p.y, a1);
        a2 = fmaf(p.z, p.z, a2); a3 = fmaf(p.w, p.w, a3);
        a0 = fmaf(q.x, q.x, a0); a1 = fmaf(q.y, q.y, a1);
        a2 = fmaf(q.z, q.z, a2); a3 = fmaf(q.w, q.w, a3);
        bf16x8 hv, lv;
        SPLIT8(p, q, hv, lv);
        *(bf16x8*)(w_hi + (c << 6) + j * 8) = hv;
        *(bf16x8*)(w_lo + (c << 6) + j * 8) = lv;
    }
    wsqh[c] = -0.5f * ((a0 + a1) + (a2 + a3));
}

// ---------------------------------------------------------------------------
// k_screen: MFMA bf16-split screen + gather.  1 wave = 32 rows (2 subtiles),
// full-K stream of 64 W code-tiles.  8 z-frags (32 VGPR) pinned loop-carried
// via empty asm so LLVM cannot sink/remat them (round-7 lesson: VGPR=72
// proved non-residency).  2048 blocks x 2 waves, launch_bounds(128,4) ->
// 16 waves/CU = 4/SIMD.  acc = dot - wsq/2 (C-init); argmin v <=> argmax acc;
// packed-int top-2 (idx in 10 low bits).  Near-ties written as -(idx+1) for
// k_rescue.  Gather writes z_q_st = W[idx] (exact: z + (zq - z) == zq).
// ---------------------------------------------------------------------------
__global__ __launch_bounds__(128, 4) void k_screen(const float* __restrict__ z_e,
                                                   const short* __restrict__ w_hi,
                                                   const short* __restrict__ w_lo,
                                                   const float* __restrict__ wsqh,
                                                   const float* __restrict__ W,
                                                   float* __restrict__ out_zq,
                                                   float* __restrict__ out_idx_f) {
    const int lane = threadIdx.x & 63;
    const int wid  = (blockIdx.x << 1) + (threadIdx.x >> 6);   // 0..4095
    const int c4 = lane >> 4, r16 = lane & 15;
    const int rowbase = wid << 5;                              // 32 rows/wave

    bf16x8 zh00, zh01, zl00, zl01, zh10, zh11, zl10, zl11;

#define LOAD_Z(S, ZH0, ZH1, ZL0, ZL1) do {                                \
    const float* zr_ = z_e + (size_t)(rowbase + (S)*16 + r16) * 64 + c4*8;\
    float4 p0_ = *(const float4*)(zr_);                                   \
    float4 q0_ = *(const float4*)(zr_ + 4);                               \
    float4 p1_ = *(const float4*)(zr_ + 32);                              \
    float4 q1_ = *(const float4*)(zr_ + 36);                              \
    SPLIT8(p0_, q0_, ZH0, ZL0);                                           \
    SPLIT8(p1_, q1_, ZH1, ZL1);                                           \
} while(0)

    LOAD_Z(0, zh00, zh01, zl00, zl01);
    LOAD_Z(1, zh10, zh11, zl10, zl11);

    int b1_0 = (int)0x80000000, b2_0 = (int)0x80000000;
    int b1_1 = (int)0x80000000, b2_1 = (int)0x80000000;
    const int vlaneor = c4 << 2;
    const short* ph = w_hi + r16 * 64 + c4 * 8;
    const short* pl = w_lo + r16 * 64 + c4 * 8;

#define SCREEN_S(ZH0, ZH1, ZL0, ZL1, B1, B2) do {                                       \
    f32x4 acc_;                                                                         \
    acc_ = __builtin_amdgcn_mfma_f32_16x16x32_bf16(whf0, ZH0, wsqf, 0, 0, 0);           \
    acc_ = __builtin_amdgcn_mfma_f32_16x16x32_bf16(whf1, ZH1, acc_, 0, 0, 0);           \
    acc_ = __builtin_amdgcn_mfma_f32_16x16x32_bf16(whf0, ZL0, acc_, 0, 0, 0);           \
    acc_ = __builtin_amdgcn_mfma_f32_16x16x32_bf16(whf1, ZL1, acc_, 0, 0, 0);           \
    acc_ = __builtin_amdgcn_mfma_f32_16x16x32_bf16(wlf0, ZH0, acc_, 0, 0, 0);           \
    acc_ = __builtin_amdgcn_mfma_f32_16x16x32_bf16(wlf1, ZH1, acc_, 0, 0, 0);           \
    _Pragma("unroll")                                                                   \
    for (int r = 0; r < 4; ++r) {                                                       \
        int u_ = (__float_as_int(acc_[r]) & (int)0xFFFFFC00) | (orbase + r);            \
        B2 = max(B2, min(u_, B1));                                                      \
        B1 = max(B1, u_);                                                               \
    }                                                                                   \
} while(0)

#pragma unroll 2
    for (int t = 0; t < 64; ++t) {
        // zero-cost pin: marks frags as loop-modified -> LLVM must keep them
        // live in VGPRs across the loop (cannot sink the loads / re-split).
        asm volatile("" : "+v"(zh00), "+v"(zh01), "+v"(zl00), "+v"(zl01),
                          "+v"(zh10), "+v"(zh11), "+v"(zl10), "+v"(zl11));
        const int cbase = t << 4;
        bf16x8 whf0 = *(const bf16x8*)(ph);
        bf16x8 whf1 = *(const bf16x8*)(ph + 32);
        bf16x8 wlf0 = *(const bf16x8*)(pl);
        bf16x8 wlf1 = *(const bf16x8*)(pl + 32);
        ph += 1024; pl += 1024;
        const f32x4 wsqf = *(const f32x4*)(wsqh + cbase + c4 * 4);
        const int orbase = cbase | vlaneor;
        SCREEN_S(zh00, zh01, zl00, zl01, b1_0, b2_0);
        SCREEN_S(zh10, zh11, zl10, zl11, b1_1, b2_1);
    }

    int idx0, idx1;

#define MERGE_S(B1, B2, IDX, ROWOFF) do {                                 \
    int x1_ = B1, x2_ = B2;                                               \
    _Pragma("unroll")                                                     \
    for (int m_ = 16; m_ <= 32; m_ <<= 1) {                               \
        int o1_ = __shfl_xor(x1_, m_);                                    \
        int o2_ = __shfl_xor(x2_, m_);                                    \
        x2_ = max(max(x2_, o2_), min(x1_, o1_));                          \
        x1_ = max(x1_, o1_);                                              \
    }                                                                     \
    float t1_ = __int_as_float(x1_ & (int)0xFFFFFC00);                    \
    float t2_ = __int_as_float(x2_ & (int)0xFFFFFC00);                    \
    IDX = x1_ & 1023;                                                     \
    bool flag_ = (t1_ - t2_) < fmaf(fabsf(t1_), 2.6e-4f, 1.6e-4f);        \
    if (lane < 16)                                                        \
        out_idx_f[rowbase + (ROWOFF) + r16] =                             \
            flag_ ? -(float)(IDX + 1) : (float)IDX;                       \
} while(0)

    MERGE_S(b1_0, b2_0, idx0, 0);
    MERGE_S(b1_1, b2_1, idx1, 16);

#define GATHER_S(S, IDX) do {                                             \
    _Pragma("unroll")                                                     \
    for (int rr = 0; rr < 4; ++rr) {                                      \
        int src_ = rr * 4 + c4;                                           \
        int iv_  = __shfl(IDX, src_);                                     \
        float4 w4_ = *(const float4*)(W + (iv_ << 6) + (r16 << 2));       \
        *(float4*)(out_zq + (size_t)(rowbase + (S)*16 + rr*4 + c4) * 64   \
                   + (r16 << 2)) = w4_;                                   \
    }                                                                     \
} while(0)

    GATHER_S(0, idx0);
    GATHER_S(1, idx1);
}

// ---------------------------------------------------------------------------
// Reference-arithmetic emulation rescue (proven rounds 3-7): numpy fp32
// pairwise sumsq + sgemm sequential-FMA dot; lowest index on fp32 ties.
// Own kernel so its zz[16]/ww[16] arrays don't pollute k_screen's regalloc.
// ---------------------------------------------------------------------------
__device__ __forceinline__ float f4c(const float4& v, int c) {
    return c == 0 ? v.x : c == 1 ? v.y : c == 2 ? v.z : v.w;
}

__device__ __forceinline__ float emu_sumsq(const float4 v[16]) {
    float s[16];
#pragma unroll
    for (int j = 0; j < 16; ++j) {
        float a = f4c(v[(j >> 2)     ], j & 3);
        float b = f4c(v[(j >> 2) + 4 ], j & 3);
        float c = f4c(v[(j >> 2) + 8 ], j & 3);
        float d = f4c(v[(j >> 2) + 12], j & 3);
        float pa = __fmul_rn(a, a), pb = __fmul_rn(b, b);
        float pc = __fmul_rn(c, c), pd = __fmul_rn(d, d);
        s[j] = __fadd_rn(__fadd_rn(pa, pb), __fadd_rn(pc, pd));
    }
    float u[8];
#pragma unroll
    for (int j = 0; j < 8; ++j) u[j] = __fadd_rn(s[j], s[j + 8]);
    float t[4];
#pragma unroll
    for (int j = 0; j < 4; ++j) t[j] = __fadd_rn(u[j], u[j + 4]);
    float w0 = __fadd_rn(t[0], t[2]);
    float w1 = __fadd_rn(t[1], t[3]);
    return __fadd_rn(w0, w1);
}

__device__ __forceinline__ int emu_row(int row, const float* __restrict__ z_e,
                                       const float* __restrict__ W, int lane) {
    float4 zz[16];
    const float4* zp = (const float4*)(z_e + ((size_t)row << 6));
#pragma unroll
    for (int j = 0; j < 16; ++j) zz[j] = zp[j];
    const float zsq = emu_sumsq(zz);

    float bestD = 1e30f;
    int   bestc = KCODES;
    for (int c0 = 0; c0 < KCODES; c0 += 64) {
        const int c = c0 + lane;
        const float4* wr = (const float4*)(W + (c << 6));
        float4 ww[16];
#pragma unroll
        for (int j = 0; j < 16; ++j) ww[j] = wr[j];
        const float wsqc = emu_sumsq(ww);
        float acc = 0.f;
#pragma unroll
        for (int j = 0; j < 16; ++j) {
            acc = __fmaf_rn(zz[j].x, ww[j].x, acc);
            acc = __fmaf_rn(zz[j].y, ww[j].y, acc);
            acc = __fmaf_rn(zz[j].z, ww[j].z, acc);
            acc = __fmaf_rn(zz[j].w, ww[j].w, acc);
        }
        const float twod = __fadd_rn(acc, acc);
        const float D = __fadd_rn(__fadd_rn(zsq, wsqc), -twod);
        if (D < bestD) { bestD = D; bestc = c; }
    }
#pragma unroll
    for (int off = 32; off > 0; off >>= 1) {
        float ov = __shfl_down(bestD, off);
        int   oc = __shfl_down(bestc, off);
        if (ov < bestD || (ov == bestD && oc < bestc)) { bestD = ov; bestc = oc; }
    }
    return __shfl(bestc, 0);
}

__global__ __launch_bounds__(64) void k_rescue(const float* __restrict__ z_e,
                                               const float* __restrict__ W,
                                               float* __restrict__ out_idx,
                                               float* __restrict__ out_zq) {
    const int lane = threadIdx.x;
    const int base = blockIdx.x * 64;
    float fi = out_idx[base + lane];
    unsigned long long m = __ballot(fi < 0.f);
    while (m) {
        int r = __ffsll(m) - 1;
        m &= m - 1;
        const int row = base + r;
        const int bc = emu_row(row, z_e, W, lane);
        if (lane == 0) out_idx[row] = (float)bc;
        if (lane < 16) {
            float4 w4 = *(const float4*)(W + (bc << 6) + (lane << 2));
            *(float4*)(out_zq + ((size_t)row << 6) + (lane << 2)) = w4;
        }
    }
}

// ---------------------------------------------------------------------------
// k_loss1/k_loss2: EXACT loss from z_e / out_zq (both losses identical in
// the forward pass: mean((z_e - z_q)^2)).  Deterministic 2-stage reduction.
// ---------------------------------------------------------------------------
__global__ __launch_bounds__(256) void k_loss1(const float* __restrict__ z_e,
                                               const float* __restrict__ zq,
                                               float* __restrict__ partials) {
    const int tid = blockIdx.x * 256 + threadIdx.x;   // 262144 threads
    float local = 0.f;
#pragma unroll
    for (int i = 0; i < 8; ++i) {
        const size_t e = (size_t)(tid + i * 262144) << 2;
        float4 z4 = *(const float4*)(z_e + e);
        float4 w4 = *(const float4*)(zq + e);
        float dx = z4.x - w4.x, dy = z4.y - w4.y;
        float dz = z4.z - w4.z, dw = z4.w - w4.w;
        local += dx * dx + dy * dy + dz * dz + dw * dw;
    }
#pragma unroll
    for (int off = 32; off > 0; off >>= 1) local += __shfl_down(local, off);
    __shared__ float s[4];
    if ((threadIdx.x & 63) == 0) s[threadIdx.x >> 6] = local;
    __syncthreads();
    if (threadIdx.x == 0) partials[blockIdx.x] = (s[0] + s[1]) + (s[2] + s[3]);
}

__global__ __launch_bounds__(256) void k_loss2(const float* __restrict__ partials,
                                               float* __restrict__ out) {
    float local = 0.f;
#pragma unroll
    for (int i = 0; i < 4; ++i) local += partials[threadIdx.x + i * 256];
#pragma unroll
    for (int off = 32; off > 0; off >>= 1) local += __shfl_down(local, off);
    __shared__ float s[4];
    if ((threadIdx.x & 63) == 0) s[threadIdx.x >> 6] = local;
    __syncthreads();
    if (threadIdx.x == 0) {
        float loss = ((s[0] + s[1]) + (s[2] + s[3])) * (1.f / 8388608.f);
        out[OUT_LOSS]     = loss;
        out[OUT_LOSS + 1] = loss;
    }
}

// ---------------------------------------------------------------------------
extern "C" void kernel_launch(void* const* d_in, const int* in_sizes, int n_in,
                              void* d_out, int out_size, void* d_ws, size_t ws_size,
                              hipStream_t stream) {
    const float* z_e = (const float*)d_in[0];
    const float* W   = (const float*)d_in[1];
    float* out       = (float*)d_out;

    short* w_hi     = (short*)d_ws;                     // 128 KB
    short* w_lo     = w_hi + KCODES * 64;               // 128 KB
    float* wsqh     = (float*)(w_lo + KCODES * 64);     // 4 KB
    float* partials = wsqh + KCODES;                    // 4 KB
    float* out_idx  = out + OUT_IDX;

    k_prep  <<<4,    256, 0, stream>>>(W, w_hi, w_lo, wsqh);
    k_screen<<<2048, 128, 0, stream>>>(z_e, w_hi, w_lo, wsqh, W, out, out_idx);
    k_rescue<<<2048, 64,  0, stream>>>(z_e, W, out_idx, out);
    k_loss1 <<<1024, 256, 0, stream>>>(z_e, out, partials);
    k_loss2 <<<1,    256, 0, stream>>>(partials, out);
}

// Round 9
// 97.317 us; speedup vs baseline: 2.3208x; 2.3208x over previous
//
#include <hip/hip_runtime.h>
#include <cstdint>

#define KCODES 1024
#define OUT_LOSS 8388608   // B*D
#define OUT_IDX  8388610   // B*D + 2 losses
#define MAXRESCUE 16384

typedef short bf16x8 __attribute__((ext_vector_type(8)));
typedef float f32x4  __attribute__((ext_vector_type(4)));
typedef unsigned u32x4 __attribute__((ext_vector_type(4)));

__device__ __forceinline__ unsigned short f2bf_rne(float f) {
    unsigned u = __float_as_uint(f);
    u += 0x7fffu + ((u >> 16) & 1u);
    return (unsigned short)(u >> 16);
}
__device__ __forceinline__ void split_pair(float a, float b, unsigned& hi, unsigned& lo) {
    unsigned ha = f2bf_rne(a), hb = f2bf_rne(b);
    hi = ha | (hb << 16);
    float ra = a - __uint_as_float(ha << 16);
    float rb = b - __uint_as_float(hb << 16);
    lo = (unsigned)f2bf_rne(ra) | ((unsigned)f2bf_rne(rb) << 16);
}

#define SPLIT8(P, Q, HV, LV) do {                                         \
    unsigned h0_,h1_,h2_,h3_,l0_,l1_,l2_,l3_;                             \
    split_pair((P).x,(P).y,h0_,l0_); split_pair((P).z,(P).w,h1_,l1_);     \
    split_pair((Q).x,(Q).y,h2_,l2_); split_pair((Q).z,(Q).w,h3_,l3_);     \
    HV = __builtin_bit_cast(bf16x8,(u32x4){h0_,h1_,h2_,h3_});             \
    LV = __builtin_bit_cast(bf16x8,(u32x4){l0_,l1_,l2_,l3_});             \
} while(0)

// ---------------------------------------------------------------------------
// k_prep: W bf16 hi/lo split + wsqh[c] = -0.5*|W_c|^2 + rescue-counter reset.
// ---------------------------------------------------------------------------
__global__ __launch_bounds__(256) void k_prep(const float* __restrict__ W,
                                              short* __restrict__ w_hi,
                                              short* __restrict__ w_lo,
                                              float* __restrict__ wsqh,
                                              int* __restrict__ rescue_cnt) {
    if (blockIdx.x == 0 && threadIdx.x == 0) rescue_cnt[0] = 0;
    const int c = blockIdx.x * 256 + threadIdx.x;
    const float4* wr = (const float4*)(W + (c << 6));
    float a0 = 0.f, a1 = 0.f, a2 = 0.f, a3 = 0.f;
#pragma unroll
    for (int j = 0; j < 8; ++j) {
        float4 p = wr[2 * j], q = wr[2 * j + 1];
        a0 = fmaf(p.x, p.x, a0); a1 = fmaf(p.y, p.y, a1);
        a2 = fmaf(p.z, p.z, a2); a3 = fmaf(p.w, p.w, a3);
        a0 = fmaf(q.x, q.x, a0); a1 = fmaf(q.y, q.y, a1);
        a2 = fmaf(q.z, q.z, a2); a3 = fmaf(q.w, q.w, a3);
        bf16x8 hv, lv;
        SPLIT8(p, q, hv, lv);
        *(bf16x8*)(w_hi + (c << 6) + j * 8) = hv;
        *(bf16x8*)(w_lo + (c << 6) + j * 8) = lv;
    }
    wsqh[c] = -0.5f * ((a0 + a1) + (a2 + a3));
}

// ---------------------------------------------------------------------------
// k_screen: LDS-staged MFMA screen (canonical GEMM pattern).
// Block = 512 thr = 8 waves x 32 rows = 256 rows.  512 blocks = 2/CU.
// W hi/lo staged through LDS in 16 double-buffered groups of 64 codes
// (16 KB/group, XOR-swizzled slots), prefetch-to-regs BEFORE compute (T14),
// ONE barrier per group.  Per wave per tile: 4 ds_read_b128 + 12 MFMA.
// Exact fp32 top-2 + idx; near-ties pushed to a compact rescue queue.
// ---------------------------------------------------------------------------
__global__ __launch_bounds__(512, 4) void k_screen(const float* __restrict__ z_e,
                                                   const short* __restrict__ w_hi,
                                                   const short* __restrict__ w_lo,
                                                   const float* __restrict__ wsqh,
                                                   const float* __restrict__ W,
                                                   float* __restrict__ out_zq,
                                                   float* __restrict__ out_idx_f,
                                                   int* __restrict__ rescue_cnt,
                                                   int* __restrict__ rescue_list) {
    __shared__ short lds_h[2][4096];    // 64 codes x 64 shorts, swizzled
    __shared__ short lds_l[2][4096];

    const int tid  = threadIdx.x;
    const int lane = tid & 63;
    const int wv   = tid >> 6;                       // 0..7
    const int c4 = lane >> 4, r16 = lane & 15;
    const int rowbase = blockIdx.x * 256 + wv * 32;  // 32 rows/wave

    // --- persistent z fragments (named; 2 subtiles of 16 rows) ---
    bf16x8 zh00, zh01, zl00, zl01, zh10, zh11, zl10, zl11;

#define LOAD_Z(S, ZH0, ZH1, ZL0, ZL1) do {                                \
    const float* zr_ = z_e + (size_t)(rowbase + (S)*16 + r16) * 64 + c4*8;\
    float4 p0_ = *(const float4*)(zr_);                                   \
    float4 q0_ = *(const float4*)(zr_ + 4);                               \
    float4 p1_ = *(const float4*)(zr_ + 32);                              \
    float4 q1_ = *(const float4*)(zr_ + 36);                              \
    SPLIT8(p0_, q0_, ZH0, ZL0);                                           \
    SPLIT8(p1_, q1_, ZH1, ZL1);                                           \
} while(0)

    LOAD_Z(0, zh00, zh01, zl00, zl01);
    LOAD_Z(1, zh10, zh11, zl10, zl11);

    // --- staging geometry: thread -> (code 0..63, slot 0..7), 16B each ---
    const int scode = tid >> 3, sslot = tid & 7;
    const short* gh = w_hi + (scode << 6) + (sslot << 3);
    const short* gl = w_lo + (scode << 6) + (sslot << 3);
    const int swz = (scode << 6) + (((sslot ^ (scode & 7))) << 3);

    {   // stage group 0 into buf 0
        bf16x8 sh = *(const bf16x8*)(gh);
        bf16x8 sl = *(const bf16x8*)(gl);
        *(bf16x8*)(lds_h[0] + swz) = sh;
        *(bf16x8*)(lds_l[0] + swz) = sl;
    }
    __syncthreads();

    float b1_0 = -3.4e38f, b2_0 = -3.4e38f;
    float b1_1 = -3.4e38f, b2_1 = -3.4e38f;
    int   i1_0 = 0, i1_1 = 0;

#define SCREEN_S(ZH0, ZH1, ZL0, ZL1, B1, B2, I1) do {                                   \
    f32x4 acc_;                                                                         \
    acc_ = __builtin_amdgcn_mfma_f32_16x16x32_bf16(whf0, ZH0, wsqf, 0, 0, 0);           \
    acc_ = __builtin_amdgcn_mfma_f32_16x16x32_bf16(whf1, ZH1, acc_, 0, 0, 0);           \
    acc_ = __builtin_amdgcn_mfma_f32_16x16x32_bf16(whf0, ZL0, acc_, 0, 0, 0);           \
    acc_ = __builtin_amdgcn_mfma_f32_16x16x32_bf16(whf1, ZL1, acc_, 0, 0, 0);           \
    acc_ = __builtin_amdgcn_mfma_f32_16x16x32_bf16(wlf0, ZH0, acc_, 0, 0, 0);           \
    acc_ = __builtin_amdgcn_mfma_f32_16x16x32_bf16(wlf1, ZH1, acc_, 0, 0, 0);           \
    _Pragma("unroll")                                                                   \
    for (int r = 0; r < 4; ++r) {                                                       \
        float v_ = acc_[r];                                                             \
        bool gt_ = v_ > B1;                                                             \
        B2 = fmaxf(B2, fminf(v_, B1));                                                  \
        B1 = fmaxf(B1, v_);                                                             \
        I1 = gt_ ? (codebase | r) : I1;                                                 \
    }                                                                                   \
} while(0)

    for (int g = 0; g < 16; ++g) {
        const int buf = g & 1;
        // keep z-frags resident (cheap pin, once per group)
        asm volatile("" : "+v"(zh00), "+v"(zh01), "+v"(zl00), "+v"(zl01),
                          "+v"(zh10), "+v"(zh11), "+v"(zl10), "+v"(zl11));
        // T14: issue next group's global loads BEFORE compute
        bf16x8 nh, nl;
        if (g < 15) {
            nh = *(const bf16x8*)(gh + ((g + 1) << 12));
            nl = *(const bf16x8*)(gl + ((g + 1) << 12));
        }
#pragma unroll
        for (int tt = 0; tt < 4; ++tt) {
            const int row = tt * 16 + r16;
            const int so  = (row << 6) + ((c4 ^ (row & 7)) << 3);
            bf16x8 whf0 = *(const bf16x8*)(lds_h[buf] + so);
            bf16x8 whf1 = *(const bf16x8*)(lds_h[buf] + (so ^ 32));
            bf16x8 wlf0 = *(const bf16x8*)(lds_l[buf] + so);
            bf16x8 wlf1 = *(const bf16x8*)(lds_l[buf] + (so ^ 32));
            const f32x4 wsqf = *(const f32x4*)(wsqh + g * 64 + tt * 16 + c4 * 4);
            const int codebase = (g * 64 + tt * 16) | (c4 << 2);
            SCREEN_S(zh00, zh01, zl00, zl01, b1_0, b2_0, i1_0);
            SCREEN_S(zh10, zh11, zl10, zl11, b1_1, b2_1, i1_1);
        }
        if (g < 15) {
            *(bf16x8*)(lds_h[buf ^ 1] + swz) = nh;
            *(bf16x8*)(lds_l[buf ^ 1] + swz) = nl;
            __syncthreads();
        }
    }

#define MERGE_S(B1, B2, I1, ROWOFF) do {                                  \
    float x1_ = B1, x2_ = B2; int i1_ = I1;                               \
    _Pragma("unroll")                                                     \
    for (int m_ = 16; m_ <= 32; m_ <<= 1) {                               \
        float o1_ = __shfl_xor(x1_, m_);                                  \
        float o2_ = __shfl_xor(x2_, m_);                                  \
        int   oi_ = __shfl_xor(i1_, m_);                                  \
        bool gt_ = o1_ > x1_;                                             \
        x2_ = gt_ ? fmaxf(x1_, o2_) : fmaxf(x2_, o1_);                    \
        x1_ = gt_ ? o1_ : x1_;                                            \
        i1_ = gt_ ? oi_ : i1_;                                            \
    }                                                                     \
    I1 = i1_;                                                             \
    if (lane < 16) {                                                      \
        const int row_ = rowbase + (ROWOFF) + r16;                        \
        out_idx_f[row_] = (float)i1_;                                     \
        bool flag_ = (x1_ - x2_) < fmaf(fabsf(x1_), 3e-5f, 6e-5f);        \
        if (flag_) {                                                      \
            int p_ = atomicAdd(rescue_cnt, 1);                            \
            if (p_ < MAXRESCUE) rescue_list[p_] = row_;                   \
        }                                                                 \
    }                                                                     \
} while(0)

    MERGE_S(b1_0, b2_0, i1_0, 0);
    MERGE_S(b1_1, b2_1, i1_1, 16);

#define GATHER_S(S, IDX) do {                                             \
    _Pragma("unroll")                                                     \
    for (int rr = 0; rr < 4; ++rr) {                                      \
        int iv_ = __shfl(IDX, rr * 4 + c4);                               \
        float4 w4_ = *(const float4*)(W + (iv_ << 6) + (r16 << 2));       \
        *(float4*)(out_zq + (size_t)(rowbase + (S)*16 + rr*4 + c4) * 64   \
                   + (r16 << 2)) = w4_;                                   \
    }                                                                     \
} while(0)

    GATHER_S(0, i1_0);
    GATHER_S(1, i1_1);
}

// ---------------------------------------------------------------------------
// Reference-arithmetic emulation (proven rounds 3-8): numpy fp32 pairwise
// sumsq + sgemm sequential-FMA dot; lowest index on fp32 ties.
// ---------------------------------------------------------------------------
__device__ __forceinline__ float f4c(const float4& v, int c) {
    return c == 0 ? v.x : c == 1 ? v.y : c == 2 ? v.z : v.w;
}

__device__ __forceinline__ float emu_sumsq(const float4 v[16]) {
    float s[16];
#pragma unroll
    for (int j = 0; j < 16; ++j) {
        float a = f4c(v[(j >> 2)     ], j & 3);
        float b = f4c(v[(j >> 2) + 4 ], j & 3);
        float c = f4c(v[(j >> 2) + 8 ], j & 3);
        float d = f4c(v[(j >> 2) + 12], j & 3);
        float pa = __fmul_rn(a, a), pb = __fmul_rn(b, b);
        float pc = __fmul_rn(c, c), pd = __fmul_rn(d, d);
        s[j] = __fadd_rn(__fadd_rn(pa, pb), __fadd_rn(pc, pd));
    }
    float u[8];
#pragma unroll
    for (int j = 0; j < 8; ++j) u[j] = __fadd_rn(s[j], s[j + 8]);
    float t[4];
#pragma unroll
    for (int j = 0; j < 4; ++j) t[j] = __fadd_rn(u[j], u[j + 4]);
    float w0 = __fadd_rn(t[0], t[2]);
    float w1 = __fadd_rn(t[1], t[3]);
    return __fadd_rn(w0, w1);
}

__device__ __forceinline__ int emu_row(int row, const float* __restrict__ z_e,
                                       const float* __restrict__ W, int lane) {
    float4 zz[16];
    const float4* zp = (const float4*)(z_e + ((size_t)row << 6));
#pragma unroll
    for (int j = 0; j < 16; ++j) zz[j] = zp[j];
    const float zsq = emu_sumsq(zz);

    float bestD = 1e30f;
    int   bestc = KCODES;
    for (int c0 = 0; c0 < KCODES; c0 += 64) {
        const int c = c0 + lane;
        const float4* wr = (const float4*)(W + (c << 6));
        float4 ww[16];
#pragma unroll
        for (int j = 0; j < 16; ++j) ww[j] = wr[j];
        const float wsqc = emu_sumsq(ww);
        float acc = 0.f;
#pragma unroll
        for (int j = 0; j < 16; ++j) {
            acc = __fmaf_rn(zz[j].x, ww[j].x, acc);
            acc = __fmaf_rn(zz[j].y, ww[j].y, acc);
            acc = __fmaf_rn(zz[j].z, ww[j].z, acc);
            acc = __fmaf_rn(zz[j].w, ww[j].w, acc);
        }
        const float twod = __fadd_rn(acc, acc);
        const float D = __fadd_rn(__fadd_rn(zsq, wsqc), -twod);
        if (D < bestD) { bestD = D; bestc = c; }
    }
#pragma unroll
    for (int off = 32; off > 0; off >>= 1) {
        float ov = __shfl_down(bestD, off);
        int   oc = __shfl_down(bestc, off);
        if (ov < bestD || (ov == bestD && oc < bestc)) { bestD = ov; bestc = oc; }
    }
    return __shfl(bestc, 0);
}

// k_rescue: grid-stride over the COMPACT flagged-row list (load-balanced).
__global__ __launch_bounds__(64) void k_rescue(const float* __restrict__ z_e,
                                               const float* __restrict__ W,
                                               const int* __restrict__ rescue_cnt,
                                               const int* __restrict__ rescue_list,
                                               float* __restrict__ out_idx,
                                               float* __restrict__ out_zq) {
    const int lane = threadIdx.x;
    const int n = min(rescue_cnt[0], MAXRESCUE);
    for (int i = blockIdx.x; i < n; i += gridDim.x) {
        const int row = rescue_list[i];
        const int bc = emu_row(row, z_e, W, lane);
        if (lane == 0) out_idx[row] = (float)bc;
        if (lane < 16) {
            float4 w4 = *(const float4*)(W + (bc << 6) + (lane << 2));
            *(float4*)(out_zq + ((size_t)row << 6) + (lane << 2)) = w4;
        }
    }
}

// ---------------------------------------------------------------------------
// k_loss1/k_loss2: EXACT loss from z_e / out_zq (both losses identical in
// the forward pass).  Deterministic 2-stage reduction.
// ---------------------------------------------------------------------------
__global__ __launch_bounds__(256) void k_loss1(const float* __restrict__ z_e,
                                               const float* __restrict__ zq,
                                               float* __restrict__ partials) {
    const int tid = blockIdx.x * 256 + threadIdx.x;   // 262144 threads
    float local = 0.f;
#pragma unroll
    for (int i = 0; i < 8; ++i) {
        const size_t e = (size_t)(tid + i * 262144) << 2;
        float4 z4 = *(const float4*)(z_e + e);
        float4 w4 = *(const float4*)(zq + e);
        float dx = z4.x - w4.x, dy = z4.y - w4.y;
        float dz = z4.z - w4.z, dw = z4.w - w4.w;
        local += dx * dx + dy * dy + dz * dz + dw * dw;
    }
#pragma unroll
    for (int off = 32; off > 0; off >>= 1) local += __shfl_down(local, off);
    __shared__ float s[4];
    if ((threadIdx.x & 63) == 0) s[threadIdx.x >> 6] = local;
    __syncthreads();
    if (threadIdx.x == 0) partials[blockIdx.x] = (s[0] + s[1]) + (s[2] + s[3]);
}

__global__ __launch_bounds__(256) void k_loss2(const float* __restrict__ partials,
                                               float* __restrict__ out) {
    float local = 0.f;
#pragma unroll
    for (int i = 0; i < 4; ++i) local += partials[threadIdx.x + i * 256];
#pragma unroll
    for (int off = 32; off > 0; off >>= 1) local += __shfl_down(local, off);
    __shared__ float s[4];
    if ((threadIdx.x & 63) == 0) s[threadIdx.x >> 6] = local;
    __syncthreads();
    if (threadIdx.x == 0) {
        float loss = ((s[0] + s[1]) + (s[2] + s[3])) * (1.f / 8388608.f);
        out[OUT_LOSS]     = loss;
        out[OUT_LOSS + 1] = loss;
    }
}

// ---------------------------------------------------------------------------
extern "C" void kernel_launch(void* const* d_in, const int* in_sizes, int n_in,
                              void* d_out, int out_size, void* d_ws, size_t ws_size,
                              hipStream_t stream) {
    const float* z_e = (const float*)d_in[0];
    const float* W   = (const float*)d_in[1];
    float* out       = (float*)d_out;

    short* w_hi      = (short*)d_ws;                    // 128 KB
    short* w_lo      = w_hi + KCODES * 64;              // 128 KB
    float* wsqh      = (float*)(w_lo + KCODES * 64);    // 4 KB
    float* partials  = wsqh + KCODES;                   // 4 KB
    int*   rcnt      = (int*)(partials + 1024);         // 4 B
    int*   rlist     = rcnt + 1;                        // 64 KB
    float* out_idx   = out + OUT_IDX;

    k_prep  <<<4,    256, 0, stream>>>(W, w_hi, w_lo, wsqh, rcnt);
    k_screen<<<512,  512, 0, stream>>>(z_e, w_hi, w_lo, wsqh, W, out, out_idx,
                                       rcnt, rlist);
    k_rescue<<<2048, 64,  0, stream>>>(z_e, W, rcnt, rlist, out_idx, out);
    k_loss1 <<<1024, 256, 0, stream>>>(z_e, out, partials);
    k_loss2 <<<1,    256, 0, stream>>>(partials, out);
}

// Round 10
// 96.133 us; speedup vs baseline: 2.3494x; 1.0123x over previous
//
#include <hip/hip_runtime.h>
#include <cstdint>

#define KCODES 1024
#define OUT_LOSS 8388608   // B*D
#define OUT_IDX  8388610   // B*D + 2 losses
#define MAXRESCUE 8192

typedef short bf16x8 __attribute__((ext_vector_type(8)));
typedef float f32x4  __attribute__((ext_vector_type(4)));
typedef unsigned u32x4 __attribute__((ext_vector_type(4)));

__device__ __forceinline__ unsigned short f2bf_rne(float f) {
    unsigned u = __float_as_uint(f);
    u += 0x7fffu + ((u >> 16) & 1u);
    return (unsigned short)(u >> 16);
}
__device__ __forceinline__ void split_pair(float a, float b, unsigned& hi, unsigned& lo) {
    unsigned ha = f2bf_rne(a), hb = f2bf_rne(b);
    hi = ha | (hb << 16);
    float ra = a - __uint_as_float(ha << 16);
    float rb = b - __uint_as_float(hb << 16);
    lo = (unsigned)f2bf_rne(ra) | ((unsigned)f2bf_rne(rb) << 16);
}

#define SPLIT8(P, Q, HV, LV) do {                                         \
    unsigned h0_,h1_,h2_,h3_,l0_,l1_,l2_,l3_;                             \
    split_pair((P).x,(P).y,h0_,l0_); split_pair((P).z,(P).w,h1_,l1_);     \
    split_pair((Q).x,(Q).y,h2_,l2_); split_pair((Q).z,(Q).w,h3_,l3_);     \
    HV = __builtin_bit_cast(bf16x8,(u32x4){h0_,h1_,h2_,h3_});             \
    LV = __builtin_bit_cast(bf16x8,(u32x4){l0_,l1_,l2_,l3_});             \
} while(0)

// ---------------------------------------------------------------------------
// k_prep: W bf16 hi/lo split + wsqh[c] = -0.5*|W_c|^2 + counter/corr reset.
// ---------------------------------------------------------------------------
__global__ __launch_bounds__(256) void k_prep(const float* __restrict__ W,
                                              short* __restrict__ w_hi,
                                              short* __restrict__ w_lo,
                                              float* __restrict__ wsqh,
                                              int* __restrict__ rescue_cnt,
                                              float* __restrict__ corr) {
    if (blockIdx.x == 0 && threadIdx.x == 0) { rescue_cnt[0] = 0; corr[0] = 0.f; }
    const int c = blockIdx.x * 256 + threadIdx.x;
    const float4* wr = (const float4*)(W + (c << 6));
    float a0 = 0.f, a1 = 0.f, a2 = 0.f, a3 = 0.f;
#pragma unroll
    for (int j = 0; j < 8; ++j) {
        float4 p = wr[2 * j], q = wr[2 * j + 1];
        a0 = fmaf(p.x, p.x, a0); a1 = fmaf(p.y, p.y, a1);
        a2 = fmaf(p.z, p.z, a2); a3 = fmaf(p.w, p.w, a3);
        a0 = fmaf(q.x, q.x, a0); a1 = fmaf(q.y, q.y, a1);
        a2 = fmaf(q.z, q.z, a2); a3 = fmaf(q.w, q.w, a3);
        bf16x8 hv, lv;
        SPLIT8(p, q, hv, lv);
        *(bf16x8*)(w_hi + (c << 6) + j * 8) = hv;
        *(bf16x8*)(w_lo + (c << 6) + j * 8) = lv;
    }
    wsqh[c] = -0.5f * ((a0 + a1) + (a2 + a3));
}

// ---------------------------------------------------------------------------
// k_screen: LDS-staged MFMA screen, 64 rows/wave, fused loss + gather.
// Block = 512 thr = 8 waves x 64 rows = 512 rows; 256 blocks (1/CU, 2 w/SIMD).
// Single lds[16384]: [buf:2][hi,lo][64 codes x 64 shorts], XOR-swizzled.
// All LDS reads = 2 base VGPRs + compile-time offsets (buf via unroll-2).
// Packed-int top-2 (idx in low 10 bits); margin 1.6e-4+2.6e-4|t1| absorbs
// 10-bit truncation (r4/5-proven).  loss_row = zsq - 2*t1f accumulated here;
// near-ties -> compact queue carrying (row, D_screen) for loss correction.
// ---------------------------------------------------------------------------
__global__ __launch_bounds__(512, 2) void k_screen(const float* __restrict__ z_e,
                                                   const short* __restrict__ w_hi,
                                                   const short* __restrict__ w_lo,
                                                   const float* __restrict__ wsqh,
                                                   const float* __restrict__ W,
                                                   float* __restrict__ out_zq,
                                                   float* __restrict__ out_idx_f,
                                                   int* __restrict__ rescue_cnt,
                                                   int2* __restrict__ rescue_list,
                                                   float* __restrict__ partials) {
    __shared__ short lds[16384];
    __shared__ float s_part[8];

    const int tid = threadIdx.x, lane = tid & 63, wv = tid >> 6;
    const int c4 = lane >> 4, r16 = lane & 15;
    const int rowbase = blockIdx.x * 512 + wv * 64;

    // --- persistent z fragments (named) + per-row |z|^2 ---
    bf16x8 zh00, zh01, zl00, zl01, zh10, zh11, zl10, zl11;
    bf16x8 zh20, zh21, zl20, zl21, zh30, zh31, zl30, zl31;
    float zsq0, zsq1, zsq2, zsq3;

#define LOAD_Z(S, ZH0, ZH1, ZL0, ZL1, ZSQ) do {                           \
    const float* zr_ = z_e + (size_t)(rowbase + (S)*16 + r16) * 64 + c4*8;\
    float4 p0_ = *(const float4*)(zr_);                                   \
    float4 q0_ = *(const float4*)(zr_ + 4);                               \
    float4 p1_ = *(const float4*)(zr_ + 32);                              \
    float4 q1_ = *(const float4*)(zr_ + 36);                              \
    SPLIT8(p0_, q0_, ZH0, ZL0);                                           \
    SPLIT8(p1_, q1_, ZH1, ZL1);                                           \
    float a_ = 0.f;                                                       \
    a_ = fmaf(p0_.x,p0_.x,a_); a_ = fmaf(p0_.y,p0_.y,a_);                 \
    a_ = fmaf(p0_.z,p0_.z,a_); a_ = fmaf(p0_.w,p0_.w,a_);                 \
    a_ = fmaf(q0_.x,q0_.x,a_); a_ = fmaf(q0_.y,q0_.y,a_);                 \
    a_ = fmaf(q0_.z,q0_.z,a_); a_ = fmaf(q0_.w,q0_.w,a_);                 \
    a_ = fmaf(p1_.x,p1_.x,a_); a_ = fmaf(p1_.y,p1_.y,a_);                 \
    a_ = fmaf(p1_.z,p1_.z,a_); a_ = fmaf(p1_.w,p1_.w,a_);                 \
    a_ = fmaf(q1_.x,q1_.x,a_); a_ = fmaf(q1_.y,q1_.y,a_);                 \
    a_ = fmaf(q1_.z,q1_.z,a_); a_ = fmaf(q1_.w,q1_.w,a_);                 \
    a_ += __shfl_xor(a_, 16); a_ += __shfl_xor(a_, 32);                   \
    ZSQ = a_;                                                             \
} while(0)

    LOAD_Z(0, zh00, zh01, zl00, zl01, zsq0);
    LOAD_Z(1, zh10, zh11, zl10, zl11, zsq1);
    LOAD_Z(2, zh20, zh21, zl20, zl21, zsq2);
    LOAD_Z(3, zh30, zh31, zl30, zl31, zsq3);

    // --- staging geometry: thread -> (code 0..63, 16B slot 0..7) ---
    const int scode = tid >> 3, sslot = tid & 7;
    const short* gph = w_hi + (scode << 6) + (sslot << 3);
    const short* gpl = w_lo + (scode << 6) + (sslot << 3);
    short* wp = lds + (scode << 6) + ((sslot ^ (scode & 7)) << 3);
    {   // stage group 0 into buf 0
        bf16x8 sh = *(const bf16x8*)gph;
        bf16x8 sl = *(const bf16x8*)gpl;
        *(bf16x8*)(wp) = sh;
        *(bf16x8*)(wp + 4096) = sl;
    }
    gph += 4096; gpl += 4096;
    __syncthreads();

    // --- hoisted LDS read bases (ks0 / ks1 slots; all else via offsets) ---
    const int slot0 = (c4 ^ (r16 & 7)) << 3;
    const short* rp0 = lds + r16 * 64 + slot0;
    const short* rp1 = lds + r16 * 64 + (slot0 ^ 32);
    const float* wsqp = wsqh + c4 * 4;

    int b1_0 = (int)0x80000000, b2_0 = (int)0x80000000;
    int b1_1 = (int)0x80000000, b2_1 = (int)0x80000000;
    int b1_2 = (int)0x80000000, b2_2 = (int)0x80000000;
    int b1_3 = (int)0x80000000, b2_3 = (int)0x80000000;
    int cb = c4 << 2;

#define SCREEN_S(ZH0, ZH1, ZL0, ZL1, B1, B2) do {                                       \
    f32x4 acc_;                                                                         \
    acc_ = __builtin_amdgcn_mfma_f32_16x16x32_bf16(whf0, ZH0, wsqf, 0, 0, 0);           \
    acc_ = __builtin_amdgcn_mfma_f32_16x16x32_bf16(whf1, ZH1, acc_, 0, 0, 0);           \
    acc_ = __builtin_amdgcn_mfma_f32_16x16x32_bf16(whf0, ZL0, acc_, 0, 0, 0);           \
    acc_ = __builtin_amdgcn_mfma_f32_16x16x32_bf16(whf1, ZL1, acc_, 0, 0, 0);           \
    acc_ = __builtin_amdgcn_mfma_f32_16x16x32_bf16(wlf0, ZH0, acc_, 0, 0, 0);           \
    acc_ = __builtin_amdgcn_mfma_f32_16x16x32_bf16(wlf1, ZH1, acc_, 0, 0, 0);           \
    _Pragma("unroll")                                                                   \
    for (int r = 0; r < 4; ++r) {                                                       \
        int u_ = (__float_as_int(acc_[r]) & (int)0xFFFFFC00) | (cb | r);                \
        B2 = max(B2, min(u_, B1));                                                      \
        B1 = max(B1, u_);                                                               \
    }                                                                                   \
} while(0)

#define PHASE(PH) do {                                                                  \
    asm volatile("" : "+v"(zh00), "+v"(zh01), "+v"(zl00), "+v"(zl01),                   \
                      "+v"(zh10), "+v"(zh11), "+v"(zl10), "+v"(zl11),                   \
                      "+v"(zh20), "+v"(zh21), "+v"(zl20), "+v"(zl21),                   \
                      "+v"(zh30), "+v"(zh31), "+v"(zl30), "+v"(zl31));                  \
    const bool pf_ = (g + (PH) + 1) < 16;                                               \
    bf16x8 nh_, nl_;                                                                    \
    if (pf_) { nh_ = *(const bf16x8*)gph; nl_ = *(const bf16x8*)gpl; }                  \
    _Pragma("unroll")                                                                   \
    for (int tt = 0; tt < 4; ++tt) {                                                    \
        bf16x8 whf0 = *(const bf16x8*)(rp0 + (PH)*8192 + tt*1024);                      \
        bf16x8 whf1 = *(const bf16x8*)(rp1 + (PH)*8192 + tt*1024);                      \
        bf16x8 wlf0 = *(const bf16x8*)(rp0 + (PH)*8192 + tt*1024 + 4096);               \
        bf16x8 wlf1 = *(const bf16x8*)(rp1 + (PH)*8192 + tt*1024 + 4096);               \
        const f32x4 wsqf = *(const f32x4*)(wsqp + (PH)*64 + tt*16);                     \
        SCREEN_S(zh00, zh01, zl00, zl01, b1_0, b2_0);                                   \
        SCREEN_S(zh10, zh11, zl10, zl11, b1_1, b2_1);                                   \
        SCREEN_S(zh20, zh21, zl20, zl21, b1_2, b2_2);                                   \
        SCREEN_S(zh30, zh31, zl30, zl31, b1_3, b2_3);                                   \
        cb += 16;                                                                       \
    }                                                                                   \
    if (pf_) {                                                                          \
        *(bf16x8*)(wp + ((PH)^1)*8192) = nh_;                                           \
        *(bf16x8*)(wp + ((PH)^1)*8192 + 4096) = nl_;                                    \
        gph += 4096; gpl += 4096;                                                       \
        __syncthreads();                                                                \
    }                                                                                   \
} while(0)

    for (int g = 0; g < 16; g += 2) {
        PHASE(0);
        PHASE(1);
        wsqp += 128;
    }

    // --- merge (idx rides in packed int), flag near-ties, loss per row ---
    int   idx0, idx1, idx2, idx3;
    float ls0, ls1, ls2, ls3;

#define MERGE_S(B1, B2, ZSQ, IDX, LOSS, ROWOFF) do {                      \
    int x1_ = B1, x2_ = B2;                                               \
    _Pragma("unroll")                                                     \
    for (int m_ = 16; m_ <= 32; m_ <<= 1) {                               \
        int o1_ = __shfl_xor(x1_, m_);                                    \
        int o2_ = __shfl_xor(x2_, m_);                                    \
        x2_ = max(max(x2_, o2_), min(x1_, o1_));                          \
        x1_ = max(x1_, o1_);                                              \
    }                                                                     \
    float t1_ = __int_as_float(x1_ & (int)0xFFFFFC00);                    \
    float t2_ = __int_as_float(x2_ & (int)0xFFFFFC00);                    \
    IDX  = x1_ & 1023;                                                    \
    LOSS = fmaf(-2.f, t1_, ZSQ);                                          \
    if (lane < 16) {                                                      \
        const int row_ = rowbase + (ROWOFF) + r16;                        \
        out_idx_f[row_] = (float)IDX;                                     \
        if ((t1_ - t2_) < fmaf(fabsf(t1_), 2.6e-4f, 1.6e-4f)) {           \
            int p_ = atomicAdd(rescue_cnt, 1);                            \
            if (p_ < MAXRESCUE)                                           \
                rescue_list[p_] = make_int2(row_, __float_as_int(LOSS));  \
        }                                                                 \
    }                                                                     \
} while(0)

    MERGE_S(b1_0, b2_0, zsq0, idx0, ls0, 0);
    MERGE_S(b1_1, b2_1, zsq1, idx1, ls1, 16);
    MERGE_S(b1_2, b2_2, zsq2, idx2, ls2, 32);
    MERGE_S(b1_3, b2_3, zsq3, idx3, ls3, 48);

    // --- block loss partial ---
    float v = (lane < 16) ? (ls0 + ls1) + (ls2 + ls3) : 0.f;
#pragma unroll
    for (int off = 32; off > 0; off >>= 1) v += __shfl_down(v, off);
    if (lane == 0) s_part[wv] = v;
    __syncthreads();
    if (tid == 0) {
        float t = 0.f;
#pragma unroll
        for (int i = 0; i < 8; ++i) t += s_part[i];
        partials[blockIdx.x] = t;
    }

    // --- gather z_q_st = W[idx] (exact) ---
#define GATHER_S(S, IDX) do {                                             \
    _Pragma("unroll")                                                     \
    for (int rr = 0; rr < 4; ++rr) {                                      \
        int iv_ = __shfl(IDX, rr * 4 + c4);                               \
        float4 w4_ = *(const float4*)(W + (iv_ << 6) + (r16 << 2));       \
        *(float4*)(out_zq + (size_t)(rowbase + (S)*16 + rr*4 + c4) * 64   \
                   + (r16 << 2)) = w4_;                                   \
    }                                                                     \
} while(0)

    GATHER_S(0, idx0);
    GATHER_S(1, idx1);
    GATHER_S(2, idx2);
    GATHER_S(3, idx3);
}

// ---------------------------------------------------------------------------
// Reference-arithmetic emulation (proven rounds 3-9): numpy fp32 pairwise
// sumsq + sgemm sequential-FMA dot; lowest index on fp32 ties.
// ---------------------------------------------------------------------------
__device__ __forceinline__ float f4c(const float4& v, int c) {
    return c == 0 ? v.x : c == 1 ? v.y : c == 2 ? v.z : v.w;
}

__device__ __forceinline__ float emu_sumsq(const float4 v[16]) {
    float s[16];
#pragma unroll
    for (int j = 0; j < 16; ++j) {
        float a = f4c(v[(j >> 2)     ], j & 3);
        float b = f4c(v[(j >> 2) + 4 ], j & 3);
        float c = f4c(v[(j >> 2) + 8 ], j & 3);
        float d = f4c(v[(j >> 2) + 12], j & 3);
        float pa = __fmul_rn(a, a), pb = __fmul_rn(b, b);
        float pc = __fmul_rn(c, c), pd = __fmul_rn(d, d);
        s[j] = __fadd_rn(__fadd_rn(pa, pb), __fadd_rn(pc, pd));
    }
    float u[8];
#pragma unroll
    for (int j = 0; j < 8; ++j) u[j] = __fadd_rn(s[j], s[j + 8]);
    float t[4];
#pragma unroll
    for (int j = 0; j < 4; ++j) t[j] = __fadd_rn(u[j], u[j + 4]);
    float w0 = __fadd_rn(t[0], t[2]);
    float w1 = __fadd_rn(t[1], t[3]);
    return __fadd_rn(w0, w1);
}

__device__ __forceinline__ void emu_row(int row, const float* __restrict__ z_e,
                                        const float* __restrict__ W, int lane,
                                        int& bc_out, float& bd_out) {
    float4 zz[16];
    const float4* zp = (const float4*)(z_e + ((size_t)row << 6));
#pragma unroll
    for (int j = 0; j < 16; ++j) zz[j] = zp[j];
    const float zsq = emu_sumsq(zz);

    float bestD = 1e30f;
    int   bestc = KCODES;
    for (int c0 = 0; c0 < KCODES; c0 += 64) {
        const int c = c0 + lane;
        const float4* wr = (const float4*)(W + (c << 6));
        float4 ww[16];
#pragma unroll
        for (int j = 0; j < 16; ++j) ww[j] = wr[j];
        const float wsqc = emu_sumsq(ww);
        float acc = 0.f;
#pragma unroll
        for (int j = 0; j < 16; ++j) {
            acc = __fmaf_rn(zz[j].x, ww[j].x, acc);
            acc = __fmaf_rn(zz[j].y, ww[j].y, acc);
            acc = __fmaf_rn(zz[j].z, ww[j].z, acc);
            acc = __fmaf_rn(zz[j].w, ww[j].w, acc);
        }
        const float twod = __fadd_rn(acc, acc);
        const float D = __fadd_rn(__fadd_rn(zsq, wsqc), -twod);
        if (D < bestD) { bestD = D; bestc = c; }
    }
#pragma unroll
    for (int off = 32; off > 0; off >>= 1) {
        float ov = __shfl_down(bestD, off);
        int   oc = __shfl_down(bestc, off);
        if (ov < bestD || (ov == bestD && oc < bestc)) { bestD = ov; bestc = oc; }
    }
    bc_out = __shfl(bestc, 0);
    bd_out = __shfl(bestD, 0);
}

// k_rescue: grid-stride over compact queue; fixes idx, zq, and loss (delta
// into corr via atomicAdd -- order wobble ~1e-17 relative, far below thresh).
__global__ __launch_bounds__(64) void k_rescue(const float* __restrict__ z_e,
                                               const float* __restrict__ W,
                                               const int* __restrict__ rescue_cnt,
                                               const int2* __restrict__ rescue_list,
                                               float* __restrict__ out_idx,
                                               float* __restrict__ out_zq,
                                               float* __restrict__ corr) {
    const int lane = threadIdx.x;
    const int n = min(rescue_cnt[0], MAXRESCUE);
    for (int i = blockIdx.x; i < n; i += gridDim.x) {
        const int2 e = rescue_list[i];
        const int row = e.x;
        int bc; float bd;
        emu_row(row, z_e, W, lane, bc, bd);
        if (lane == 0) {
            out_idx[row] = (float)bc;
            atomicAdd(corr, bd - __int_as_float(e.y));
        }
        if (lane < 16) {
            float4 w4 = *(const float4*)(W + (bc << 6) + (lane << 2));
            *(float4*)(out_zq + ((size_t)row << 6) + (lane << 2)) = w4;
        }
    }
}

// ---------------------------------------------------------------------------
// k_loss2: reduce 256 block partials + rescue correction (both losses
// identical in forward: mean((z_e - z_q)^2)).
// ---------------------------------------------------------------------------
__global__ __launch_bounds__(256) void k_loss2(const float* __restrict__ partials,
                                               const float* __restrict__ corr,
                                               float* __restrict__ out) {
    float local = partials[threadIdx.x];
#pragma unroll
    for (int off = 32; off > 0; off >>= 1) local += __shfl_down(local, off);
    __shared__ float s[4];
    if ((threadIdx.x & 63) == 0) s[threadIdx.x >> 6] = local;
    __syncthreads();
    if (threadIdx.x == 0) {
        float loss = (((s[0] + s[1]) + (s[2] + s[3])) + corr[0]) * (1.f / 8388608.f);
        out[OUT_LOSS]     = loss;
        out[OUT_LOSS + 1] = loss;
    }
}

// ---------------------------------------------------------------------------
extern "C" void kernel_launch(void* const* d_in, const int* in_sizes, int n_in,
                              void* d_out, int out_size, void* d_ws, size_t ws_size,
                              hipStream_t stream) {
    const float* z_e = (const float*)d_in[0];
    const float* W   = (const float*)d_in[1];
    float* out       = (float*)d_out;

    short* w_hi      = (short*)d_ws;                    // 128 KB
    short* w_lo      = w_hi + KCODES * 64;              // 128 KB
    float* wsqh      = (float*)(w_lo + KCODES * 64);    // 4 KB
    float* partials  = wsqh + KCODES;                   // 1 KB
    int2*  rlist     = (int2*)(partials + 256);         // 64 KB (8B-aligned)
    int*   rcnt      = (int*)(rlist + MAXRESCUE);
    float* corr      = (float*)(rcnt + 1);
    float* out_idx   = out + OUT_IDX;

    k_prep  <<<4,    256, 0, stream>>>(W, w_hi, w_lo, wsqh, rcnt, corr);
    k_screen<<<256,  512, 0, stream>>>(z_e, w_hi, w_lo, wsqh, W, out, out_idx,
                                       rcnt, rlist, partials);
    k_rescue<<<1024, 64,  0, stream>>>(z_e, W, rcnt, rlist, out_idx, out, corr);
    k_loss2 <<<1,    256, 0, stream>>>(partials, corr, out);
}